// Round 6
// baseline (59.122 us; speedup 1.0000x reference)
//
#include <hip/hip_runtime.h>

// 256 independent MLPs (2->32->2), 16384 rows. VALU-bound.
// Round 6: lane=channel, thread=16 rows. Weights repacked [h][c][*] into d_ws
// -> per-lane VGPR operands (coalesced, no splats); x rows readfirstlane'd to
// SGPR (1 SGPR per v_fma = legal); abs/neg as VOP3 modifiers. 13 VALU/eval,
// 16 independent chains/wave for ILP. Direct coalesced 512B stores, no LDS.

#define NCH   256
#define HID   32
#define BATCH 16384
#define TPB   64    // one wave; lane = channel within group
#define ROWS  16    // batch rows per thread

// d_ws layout (floats): W0p[HID][NCH][2] | b0p[HID][NCH] | W1p[HID][NCH][2]
#define W0P_OFF 0
#define B0P_OFF (HID * NCH * 2)
#define W1P_OFF (B0P_OFF + HID * NCH)
#define WS_FLOATS (W1P_OFF + HID * NCH * 2)   // 40960 floats = 160 KB

__global__ __launch_bounds__(256) void repack_kernel(
    const float* __restrict__ W0,   // [NCH][HID][2]
    const float* __restrict__ b0,   // [NCH][HID]
    const float* __restrict__ W1,   // [NCH][2][HID]
    float* __restrict__ ws)
{
    int t = blockIdx.x * blockDim.x + threadIdx.x;   // 16384 threads
    {   // W0p[(h*NCH + c)*2 + i] = W0[c*64 + h*2 + i]
        int i = t & 1, c = (t >> 1) & 255, h = t >> 9;
        ws[W0P_OFF + t] = W0[c * (HID * 2) + h * 2 + i];
    }
    if (t < HID * NCH) {   // b0p[h*NCH + c] = b0[c*32 + h]
        int c = t & 255, h = t >> 8;
        ws[B0P_OFF + t] = b0[c * HID + h];
    }
    {   // W1p[(h*NCH + c)*2 + o] = W1[c*64 + o*32 + h]
        int o = t & 1, c = (t >> 1) & 255, h = t >> 9;
        ws[W1P_OFF + t] = W1[c * (2 * HID) + o * HID + h];
    }
}

static __device__ __forceinline__ float rfl(float v) {
    return __uint_as_float(__builtin_amdgcn_readfirstlane(__float_as_uint(v)));
}

__global__ __launch_bounds__(TPB, 4) void mlp_main(
    const float* __restrict__ x,    // [BATCH][2]
    const float* __restrict__ ws,   // repacked weights
    const float* __restrict__ b1,   // [NCH][2]
    float* __restrict__ out)        // [BATCH][NCH][2]
{
    // A&S 7.1.27 erf poly, sqrt(2) folded (|eps|<=5e-4); q = 2*gelu.
    const float A1 = 0.19685390f;
    const float A2 = 0.11519450f;
    const float A3 = 3.4365516e-4f;
    const float A4 = 0.019527f;

    const float2* __restrict__ W0p = (const float2*)(ws + W0P_OFF);  // [h*NCH+c] -> (wa,wb)
    const float*  __restrict__ b0p = ws + B0P_OFF;                   // [h*NCH+c]
    const float2* __restrict__ W1p = (const float2*)(ws + W1P_OFF);  // [h*NCH+c] -> (w1a,w1b)

    const int lane  = threadIdx.x;
    const int cb    = blockIdx.x & 3;        // channel group (4)
    const int rb    = blockIdx.x >> 2;       // row block (1024)
    const int c     = cb * 64 + lane;
    const int rbase = rb * ROWS;

    // x rows -> SGPRs (wave-uniform)
    float sx0[ROWS], sx1[ROWS];
    const float2* __restrict__ x2 = (const float2*)x;
    #pragma unroll
    for (int r = 0; r < ROWS; ++r) {
        float2 xr = x2[rbase + r];
        sx0[r] = rfl(xr.x);
        sx1[r] = rfl(xr.y);
    }

    float acc0[ROWS], acc1[ROWS];
    #pragma unroll
    for (int r = 0; r < ROWS; ++r) { acc0[r] = 0.0f; acc1[r] = 0.0f; }

    for (int h = 0; h < HID; ++h) {
        const float2 w0v = W0p[h * NCH + c];   // per-lane, coalesced 512B
        const float  bh  = b0p[h * NCH + c];
        const float2 w1v = W1p[h * NCH + c];

        #pragma unroll
        for (int r = 0; r < ROWS; ++r) {
            float pre = fmaf(sx0[r], w0v.x, fmaf(sx1[r], w0v.y, bh));
            float a   = __builtin_fabsf(pre);            // VOP3 abs modifier
            float t   = fmaf(A4, a, A3);
            t         = fmaf(t, a, A2);
            t         = fmaf(t, a, A1);
            float P   = fmaf(t, a, 1.0f);
            float P2  = P * P;
            float P4  = P2 * P2;
            float inv = __builtin_amdgcn_rcpf(P4);       // 1/P^4
            float q   = fmaf(-a, inv, pre + a);          // 2*gelu
            acc0[r]   = fmaf(q, w1v.x, acc0[r]);
            acc1[r]   = fmaf(q, w1v.y, acc1[r]);
        }
    }

    // Direct coalesced writeback: lanes consecutive in c -> 512B per row
    const float2 b1v = ((const float2*)b1)[c];
    float2* __restrict__ out2 = (float2*)out;
    #pragma unroll
    for (int r = 0; r < ROWS; ++r) {
        out2[(size_t)(rbase + r) * NCH + c] =
            make_float2(fmaf(0.5f, acc0[r], b1v.x), fmaf(0.5f, acc1[r], b1v.y));
    }
}

extern "C" void kernel_launch(void* const* d_in, const int* in_sizes, int n_in,
                              void* d_out, int out_size, void* d_ws, size_t ws_size,
                              hipStream_t stream) {
    const float* x  = (const float*)d_in[0];
    const float* W0 = (const float*)d_in[1];
    const float* b0 = (const float*)d_in[2];
    const float* W1 = (const float*)d_in[3];
    const float* b1 = (const float*)d_in[4];
    float* out = (float*)d_out;
    float* ws  = (float*)d_ws;   // needs 160 KB

    repack_kernel<<<dim3(HID * NCH * 2 / 256), dim3(256), 0, stream>>>(W0, b0, W1, ws);

    dim3 grid((BATCH / ROWS) * (NCH / TPB));   // 1024 * 4 = 4096
    mlp_main<<<grid, dim3(TPB), 0, stream>>>(x, ws, b1, out);
}